// Round 1
// baseline (114.813 us; speedup 1.0000x reference)
//
#include <hip/hip_runtime.h>
#include <math.h>

#define HW 4096

typedef __attribute__((ext_vector_type(8))) short short8;
typedef __attribute__((ext_vector_type(8))) _Float16 half8;
typedef __attribute__((ext_vector_type(4))) float floatx4;

// ---- bf16 helpers (round-to-nearest-even) ----
__device__ inline float bflo(unsigned u) { return __uint_as_float(u << 16); }
__device__ inline float bfhi(unsigned u) { return __uint_as_float(u & 0xffff0000u); }
__device__ inline unsigned short f2bf(float x) {
    unsigned u = __float_as_uint(x);
    return (unsigned short)((u + 0x7fffu + ((u >> 16) & 1u)) >> 16);
}
__device__ inline unsigned f2bf2(float lo, float hi) {
    unsigned a = __float_as_uint(lo), b = __float_as_uint(hi);
    a = (a + 0x7fffu + ((a >> 16) & 1u)) >> 16;
    b = (b + 0x7fffu + ((b >> 16) & 1u)) & 0xffff0000u;
    return a | b;
}
__device__ inline unsigned short f2h(float x) {
    _Float16 h = (_Float16)x;
    return __builtin_bit_cast(unsigned short, h);
}

// ws layout (bytes):
//   qkv1b @ 0        : 2*18*4096*32*2 = 9437184  bf16 [b][g][px][32] (pre-dw)
//   attnO @ 9437184  : 2*4096*192*2 = 3145728    bf16 [b*px][c]

// ---------------------------------------------------------------------------
// K1: QKV 1x1 conv as bf16 MFMA GEMM, M=8192(px) N=576(oc) K=192.
// (unchanged from previous round)
// ---------------------------------------------------------------------------
__global__ __launch_bounds__(256) void k_gq(const float* __restrict__ x,
    const float* __restrict__ W1, const float* __restrict__ b1,
    unsigned short* __restrict__ qkv)
{
    __shared__ __align__(16) unsigned short As[64 * 200];
    __shared__ __align__(16) unsigned short Bs[64 * 200];
    const int t = threadIdx.x;
    const int m0 = blockIdx.x * 64;
    const int n0 = blockIdx.y * 64;
    const int w = t >> 6, lane = t & 63;
    const int b = m0 >> 12, px0 = m0 & 4095;
    // ---- A: transpose-convert 64px x 192c ----
    {
        const float* xb = x + ((size_t)(b * 192) << 12) + px0 + lane;
        const int cb = w * 48;
        #pragma unroll
        for (int r4 = 0; r4 < 12; ++r4) {
            float v0 = xb[(size_t)(cb + r4 * 4 + 0) << 12];
            float v1 = xb[(size_t)(cb + r4 * 4 + 1) << 12];
            float v2 = xb[(size_t)(cb + r4 * 4 + 2) << 12];
            float v3 = xb[(size_t)(cb + r4 * 4 + 3) << 12];
            *(uint2*)&As[lane * 200 + cb + r4 * 4] =
                make_uint2(f2bf2(v0, v1), f2bf2(v2, v3));
        }
    }
    // ---- B: convert W1 slice [n0..n0+63][192] ----
    #pragma unroll
    for (int pass = 0; pass < 12; ++pass) {
        int idx = pass * 256 + t;
        int row = idx / 48, ch = idx - row * 48;
        float4 wv = *(const float4*)&W1[(size_t)(n0 + row) * 192 + ch * 4];
        *(uint2*)&Bs[row * 200 + ch * 4] =
            make_uint2(f2bf2(wv.x, wv.y), f2bf2(wv.z, wv.w));
    }
    __syncthreads();
    const int lm = lane & 15, lq = lane >> 4;
    floatx4 acc[4] = {};
    #pragma unroll
    for (int ks = 0; ks < 6; ++ks) {
        short8 bf = *(const short8*)&Bs[(w * 16 + lm) * 200 + ks * 32 + lq * 8];
        #pragma unroll
        for (int mt = 0; mt < 4; ++mt) {
            short8 af = *(const short8*)&As[(mt * 16 + lm) * 200 + ks * 32 + lq * 8];
            acc[mt] = __builtin_amdgcn_mfma_f32_16x16x32_bf16(af, bf, acc[mt], 0, 0, 0);
        }
    }
    __syncthreads();
    const float bias = b1[n0 + w * 16 + lm];
    #pragma unroll
    for (int mt = 0; mt < 4; ++mt)
        #pragma unroll
        for (int r = 0; r < 4; ++r)
            As[(mt * 16 + lq * 4 + r) * 72 + w * 16 + lm] = f2bf(acc[mt][r] + bias);
    __syncthreads();
    #pragma unroll
    for (int pass = 0; pass < 2; ++pass) {
        int idx = pass * 256 + t;           // 64 m x 8 n-groups
        int m = idx >> 3, n8 = idx & 7;
        uint4 val = *(const uint4*)&As[m * 72 + n8 * 8];
        int oc = n0 + n8 * 8;
        int g = oc >> 5, d = oc & 31;
        *(uint4*)&qkv[((((size_t)(b * 18 + g) << 12) + px0 + m) << 5) + d] = val;
    }
}

// ---------------------------------------------------------------------------
// K2: MFMA neighborhood attention with FUSED depthwise 3x3.
// Block 256 = (b, head, 8x8 tile), 4 waves.
// Staging now reads pre-dw qkv1b and computes the 3x3 depthwise (fp32, SAME
// zero-pad via guards, bias from dwB) on the fly for:
//   - K halo (14x14 px -> l2norm -> Ks bf16)
//   - V halo (14x14 px -> Vts f16 transposed)
//   - Q tile (per-lane 8-ch fragment -> l2norm -> bq)
// W2/b2 slices for this head staged in LDS (dwW [3][9][32], dwB [3][32]).
// Rest (QK^T mfma, mask+bias+softmax, PV mfma) unchanged.
// ---------------------------------------------------------------------------
__global__ __launch_bounds__(256) void k_attn(const unsigned short* __restrict__ qkv,
    const float* __restrict__ W2, const float* __restrict__ b2,
    const float* __restrict__ temp, const float* __restrict__ rpb,
    unsigned short* __restrict__ attnO)
{
    __shared__ __align__(16) char lds[49088];
    unsigned short* Ks  = (unsigned short*)lds;            // [208][40] bf16
    unsigned short* Ps  = (unsigned short*)lds;            // [64][232] f16 (alias)
    unsigned short* Vts = (unsigned short*)(lds + 29696);  // [32][232] f16
    float* rpbs = (float*)(lds + 44544);                   // [169]
    float* dwW  = (float*)(lds + 45248);                   // [3][9][32] plane-major
    float* dwB  = (float*)(lds + 48704);                   // [3][32]

    const int t = threadIdx.x;
    const int head = blockIdx.y, b = blockIdx.z;

    // ---- stage dw weights/bias + rpb ----
    for (int idx = t; idx < 864; idx += 256) {
        int plane = idx / 288, rem = idx - plane * 288;
        dwW[idx] = W2[(plane * 192 + head * 32 + (rem & 31)) * 9 + (rem >> 5)];
    }
    if (t < 96) dwB[t] = b2[(t >> 5) * 192 + head * 32 + (t & 31)];
    if (t < 169) rpbs[t] = rpb[head * 169 + t];
    __syncthreads();

    const int ti = blockIdx.x >> 3, tj = blockIdx.x & 7;
    const int i0 = ti * 8, j0 = tj * 8;
    const int r0 = min(max(i0 - 3, 0), 50), c0 = min(max(j0 - 3, 0), 50);
    const unsigned short* qpl = qkv + ((size_t)(b * 18 + head) << 17);
    const unsigned short* kpl = qkv + ((size_t)(b * 18 + 6 + head) << 17);
    const unsigned short* vpl = qkv + ((size_t)(b * 18 + 12 + head) << 17);

    // ---- stage K-hat (dw + l2norm, bf16) and V^T (dw, f16) ----
    if (t < 196) {
        int r = (t * 2341) >> 15, cc = t - r * 14;
        const int pi = r0 + r, pj = c0 + cc;
        float acc[32];
        // K plane depthwise
        #pragma unroll
        for (int e = 0; e < 32; ++e) acc[e] = dwB[32 + e];
        #pragma unroll
        for (int di = -1; di <= 1; ++di) {
            int ii = pi + di;
            if (ii < 0 || ii > 63) continue;
            #pragma unroll
            for (int dj = -1; dj <= 1; ++dj) {
                int jj = pj + dj;
                if (jj < 0 || jj > 63) continue;
                const float* wt = &dwW[(9 + (di + 1) * 3 + dj + 1) * 32];
                const uint4* kg = (const uint4*)(kpl + (((ii << 6) + jj) << 5));
                #pragma unroll
                for (int q = 0; q < 4; ++q) {
                    uint4 u = kg[q];
                    unsigned uu[4] = {u.x, u.y, u.z, u.w};
                    #pragma unroll
                    for (int e = 0; e < 4; ++e) {
                        acc[q * 8 + e * 2]     = fmaf(bflo(uu[e]), wt[q * 8 + e * 2],     acc[q * 8 + e * 2]);
                        acc[q * 8 + e * 2 + 1] = fmaf(bfhi(uu[e]), wt[q * 8 + e * 2 + 1], acc[q * 8 + e * 2 + 1]);
                    }
                }
            }
        }
        float ss = 0.f;
        #pragma unroll
        for (int e = 0; e < 32; ++e) ss = fmaf(acc[e], acc[e], ss);
        float rinv = 1.0f / fmaxf(sqrtf(ss), 1e-12f);
        #pragma unroll
        for (int q = 0; q < 4; ++q) {
            uint4 p;
            p.x = f2bf2(acc[q * 8 + 0] * rinv, acc[q * 8 + 1] * rinv);
            p.y = f2bf2(acc[q * 8 + 2] * rinv, acc[q * 8 + 3] * rinv);
            p.z = f2bf2(acc[q * 8 + 4] * rinv, acc[q * 8 + 5] * rinv);
            p.w = f2bf2(acc[q * 8 + 6] * rinv, acc[q * 8 + 7] * rinv);
            *(uint4*)&Ks[t * 40 + q * 8] = p;
        }
        // V plane depthwise -> transposed f16
        #pragma unroll
        for (int e = 0; e < 32; ++e) acc[e] = dwB[64 + e];
        #pragma unroll
        for (int di = -1; di <= 1; ++di) {
            int ii = pi + di;
            if (ii < 0 || ii > 63) continue;
            #pragma unroll
            for (int dj = -1; dj <= 1; ++dj) {
                int jj = pj + dj;
                if (jj < 0 || jj > 63) continue;
                const float* wt = &dwW[(18 + (di + 1) * 3 + dj + 1) * 32];
                const uint4* vg = (const uint4*)(vpl + (((ii << 6) + jj) << 5));
                #pragma unroll
                for (int q = 0; q < 4; ++q) {
                    uint4 u = vg[q];
                    unsigned uu[4] = {u.x, u.y, u.z, u.w};
                    #pragma unroll
                    for (int e = 0; e < 4; ++e) {
                        acc[q * 8 + e * 2]     = fmaf(bflo(uu[e]), wt[q * 8 + e * 2],     acc[q * 8 + e * 2]);
                        acc[q * 8 + e * 2 + 1] = fmaf(bfhi(uu[e]), wt[q * 8 + e * 2 + 1], acc[q * 8 + e * 2 + 1]);
                    }
                }
            }
        }
        #pragma unroll
        for (int e = 0; e < 32; ++e) Vts[e * 232 + t] = f2h(acc[e]);
    }
    // zero V^T cols 196..223 (PV pad region must be 0)
    for (int idx = t; idx < 448; idx += 256) {
        int row = (idx * 2341) >> 15;
        int c = idx - row * 14;
        ((unsigned*)(Vts + row * 232))[98 + c] = 0u;
    }

    // ---- q: fused dw + l2norm, fragment in registers ----
    const int w = t >> 6, lane = t & 63;
    const int lm = lane & 15, lq = lane >> 4;
    const int px = w * 16 + lm;
    const int i = i0 + (px >> 3), j = j0 + (px & 7);
    float qf[8];
    #pragma unroll
    for (int e = 0; e < 8; ++e) qf[e] = dwB[lq * 8 + e];
    #pragma unroll
    for (int di = -1; di <= 1; ++di) {
        int ii = i + di;
        if (ii < 0 || ii > 63) continue;
        #pragma unroll
        for (int dj = -1; dj <= 1; ++dj) {
            int jj = j + dj;
            if (jj < 0 || jj > 63) continue;
            const float* wt = &dwW[((di + 1) * 3 + dj + 1) * 32 + lq * 8];
            uint4 u = *(const uint4*)(qpl + ((((ii << 6) + jj) << 5) + lq * 8));
            unsigned uu[4] = {u.x, u.y, u.z, u.w};
            #pragma unroll
            for (int e = 0; e < 4; ++e) {
                qf[e * 2]     = fmaf(bflo(uu[e]), wt[e * 2],     qf[e * 2]);
                qf[e * 2 + 1] = fmaf(bfhi(uu[e]), wt[e * 2 + 1], qf[e * 2 + 1]);
            }
        }
    }
    float qs = 0.f;
    #pragma unroll
    for (int e = 0; e < 8; ++e) qs = fmaf(qf[e], qf[e], qs);
    qs += __shfl_xor(qs, 16);
    qs += __shfl_xor(qs, 32);
    float qinv = 1.0f / fmaxf(sqrtf(qs), 1e-12f);
    short8 bq;
    #pragma unroll
    for (int e = 0; e < 8; ++e) bq[e] = (short)f2bf(qf[e] * qinv);
    __syncthreads();

    // ---- QK^T: S^T[nbr][px], 13 n-tiles of 16 nbrs ----
    floatx4 acc[13];
    #pragma unroll
    for (int mt = 0; mt < 13; ++mt) {
        short8 ak = *(const short8*)&Ks[(mt * 16 + lm) * 40 + lq * 8];
        floatx4 z = {0.f, 0.f, 0.f, 0.f};
        acc[mt] = __builtin_amdgcn_mfma_f32_16x16x32_bf16(ak, bq, z, 0, 0, 0);
    }
    __syncthreads();                        // Ks dead; Ps may overwrite

    // ---- mask + bias + softmax ----
    const int si = min(max(i - 3, 0), 57), sj = min(max(j - 3, 0), 57);
    const int vloi = si - r0, vloj = sj - c0;
    const int oi = r0 - i + 6, oj = c0 - j + 6;
    const float th = temp[head];
    float mx = -1e30f;
    #pragma unroll
    for (int mt = 0; mt < 13; ++mt) {
        int nb0 = mt * 16 + lq * 4;
        int rh0 = (nb0 * 2341) >> 15;
        int ch0 = nb0 - rh0 * 14;
        #pragma unroll
        for (int r = 0; r < 4; ++r) {
            int ch = ch0 + r, rh = rh0;
            if (ch >= 14) { ch -= 14; rh += 1; }
            int bidx = (rh + oi) * 13 + (ch + oj);
            float bias = rpbs[max(0, min(168, bidx))];
            bool valid = ((unsigned)(rh - vloi) <= 6u) && ((unsigned)(ch - vloj) <= 6u);
            float s = (acc[mt][r] + bias) * th;
            s = valid ? s : -1e30f;
            acc[mt][r] = s;
            mx = fmaxf(mx, s);
        }
    }
    mx = fmaxf(mx, __shfl_xor(mx, 16));
    mx = fmaxf(mx, __shfl_xor(mx, 32));
    float ssum = 0.f;
    #pragma unroll
    for (int mt = 0; mt < 13; ++mt)
        #pragma unroll
        for (int r = 0; r < 4; ++r) {
            float e = __expf(acc[mt][r] - mx);
            acc[mt][r] = e;
            ssum += e;
        }
    ssum += __shfl_xor(ssum, 16);
    ssum += __shfl_xor(ssum, 32);
    const float rs = 1.0f / ssum;

    if (lane < 32) {                       // zero Ps pad cols 208..223
        uint4 z4 = {0u, 0u, 0u, 0u};
        *(uint4*)&Ps[(w * 16 + (lane >> 1)) * 232 + 208 + (lane & 1) * 8] = z4;
    }
    #pragma unroll
    for (int mt = 0; mt < 13; ++mt) {
        unsigned lo = (unsigned)f2h(acc[mt][0] * rs) | ((unsigned)f2h(acc[mt][1] * rs) << 16);
        unsigned hi = (unsigned)f2h(acc[mt][2] * rs) | ((unsigned)f2h(acc[mt][3] * rs) << 16);
        *(uint2*)&Ps[px * 232 + mt * 16 + lq * 4] = make_uint2(lo, hi);
    }
    __syncthreads();

    // ---- PV: O[px][d] = P x V^T ----
    floatx4 oacc[2] = {};
    #pragma unroll
    for (int ks = 0; ks < 7; ++ks) {
        half8 ap = *(const half8*)&Ps[(w * 16 + lm) * 232 + ks * 32 + lq * 8];
        #pragma unroll
        for (int n2 = 0; n2 < 2; ++n2) {
            half8 bv = *(const half8*)&Vts[(n2 * 16 + lm) * 232 + ks * 32 + lq * 8];
            oacc[n2] = __builtin_amdgcn_mfma_f32_16x16x32_f16(ap, bv, oacc[n2], 0, 0, 0);
        }
    }
    #pragma unroll
    for (int n2 = 0; n2 < 2; ++n2)
        #pragma unroll
        for (int r = 0; r < 4; ++r) {
            int p2 = w * 16 + lq * 4 + r;
            int i2 = i0 + (p2 >> 3), j2 = j0 + (p2 & 7);
            attnO[((size_t)((b << 12) + (i2 << 6) + j2)) * 192 + head * 32 + n2 * 16 + lm]
                = f2bf(oacc[n2][r]);
        }
}

// ---------------------------------------------------------------------------
// K4: proj 1x1 as bf16 MFMA GEMM. M=8192 N=192 K=192. (unchanged)
// ---------------------------------------------------------------------------
__global__ __launch_bounds__(256) void k_gp(const unsigned short* __restrict__ Ain,
    const float* __restrict__ Wp, const float* __restrict__ bp,
    float* __restrict__ out)
{
    __shared__ __align__(16) unsigned short As[64 * 200];
    __shared__ __align__(16) unsigned short Bs[64 * 200];
    const int t = threadIdx.x;
    const int m0 = blockIdx.x * 64;
    const int n0 = blockIdx.y * 64;
    #pragma unroll
    for (int pass = 0; pass < 6; ++pass) {
        int idx = pass * 256 + t;
        int m = idx / 24, c16 = idx % 24;
        *(uint4*)&As[m * 200 + c16 * 8] = *(const uint4*)&Ain[(size_t)(m0 + m) * 192 + c16 * 8];
    }
    #pragma unroll
    for (int pass = 0; pass < 12; ++pass) {
        int idx = pass * 256 + t;
        int row = idx / 48, ch = idx - row * 48;
        float4 wv = *(const float4*)&Wp[(size_t)(n0 + row) * 192 + ch * 4];
        *(uint2*)&Bs[row * 200 + ch * 4] =
            make_uint2(f2bf2(wv.x, wv.y), f2bf2(wv.z, wv.w));
    }
    __syncthreads();
    const int w = t >> 6, lane = t & 63;
    const int lm = lane & 15, lq = lane >> 4;
    floatx4 acc[4] = {};
    #pragma unroll
    for (int ks = 0; ks < 6; ++ks) {
        short8 bf = *(const short8*)&Bs[(w * 16 + lm) * 200 + ks * 32 + lq * 8];
        #pragma unroll
        for (int mt = 0; mt < 4; ++mt) {
            short8 af = *(const short8*)&As[(mt * 16 + lm) * 200 + ks * 32 + lq * 8];
            acc[mt] = __builtin_amdgcn_mfma_f32_16x16x32_bf16(af, bf, acc[mt], 0, 0, 0);
        }
    }
    __syncthreads();
    float* fs = (float*)As;                 // [n][m] stride 68
    const float bias = bp[n0 + w * 16 + lm];
    #pragma unroll
    for (int mt = 0; mt < 4; ++mt)
        #pragma unroll
        for (int r = 0; r < 4; ++r)
            fs[(w * 16 + lm) * 68 + mt * 16 + lq * 4 + r] = acc[mt][r] + bias;
    __syncthreads();
    const int b = m0 >> 12, px0 = m0 & 4095;
    #pragma unroll
    for (int pass = 0; pass < 4; ++pass) {
        int idx = pass * 256 + t;           // 64 n x 16 m-quads
        int n = idx >> 4, m4 = idx & 15;
        float4 val = *(const float4*)&fs[n * 68 + m4 * 4];
        *(float4*)&out[((size_t)(b * 192 + n0 + n) << 12) + px0 + m4 * 4] = val;
    }
}

extern "C" void kernel_launch(void* const* d_in, const int* in_sizes, int n_in,
                              void* d_out, int out_size, void* d_ws, size_t ws_size,
                              hipStream_t stream) {
    const float* x    = (const float*)d_in[0];
    const float* W1   = (const float*)d_in[1];
    const float* b1   = (const float*)d_in[2];
    const float* W2   = (const float*)d_in[3];
    const float* b2   = (const float*)d_in[4];
    const float* temp = (const float*)d_in[5];
    const float* rpb  = (const float*)d_in[6];
    const float* Wp   = (const float*)d_in[7];
    const float* bp   = (const float*)d_in[8];
    float* out = (float*)d_out;

    char* ws = (char*)d_ws;
    unsigned short* qkv1b = (unsigned short*)(ws);
    unsigned short* attnO = (unsigned short*)(ws + 9437184);

    k_gq  <<<dim3(128, 9), 256, 0, stream>>>(x, W1, b1, qkv1b);
    k_attn<<<dim3(64, 6, 2), 256, 0, stream>>>(qkv1b, W2, b2, temp, rpb, attnO);
    k_gp  <<<dim3(128, 3), 256, 0, stream>>>(attnO, Wp, bp, out);
}